// Round 13
// baseline (181.838 us; speedup 1.0000x reference)
//
#include <hip/hip_runtime.h>
#include <hip/hip_bf16.h>
#include <stdint.h>

// B=2, S=2048, D=1024, H=16, Hd=64.  Inputs/outputs FP32; internal bf16 MFMA.
// R23 = R22 (171.2us) + attn barrier-domain split: Q-tile 128 -> 64, block
// 512 -> 256 threads (4 waves), grid 512 -> 1024 = 4 blocks/CU.  Per-wave
// code byte-identical (32q x 32k wave, register-P, permuted-V b128 B-frag,
// MFMA ones-column l); only staging (4 gl_lds/thread), id decode, and the
// 2-wave epilogue change.  4 independent barrier groups per CU overlap one
// block's staging drain with three others' compute (total waves/CU unchanged
// at 16).  Cost: 2x K/V staging traffic, L2-resident.
// gemms (BK=64, coalesced epilogues) and cvt unchanged.

typedef __bf16 bf16;
typedef __attribute__((ext_vector_type(8))) __bf16 bf16x8;
typedef __attribute__((ext_vector_type(4))) __bf16 bf16x4;
typedef __attribute__((ext_vector_type(4))) float f32x4;

#define DEVI __device__ __forceinline__

DEVI void gl_lds16(const void* g, void* l) {
  __builtin_amdgcn_global_load_lds(
      (const __attribute__((address_space(1))) void*)g,
      (__attribute__((address_space(3))) void*)l, 16, 0, 0);
}

DEVI bf16x8 load8(const bf16* p) { return *(const bf16x8*)p; }
DEVI bf16x8 load8(const float* p) {
  f32x4 a = *(const f32x4*)p;
  f32x4 b = *(const f32x4*)(p + 4);
  bf16x8 r;
  r[0] = (bf16)a[0]; r[1] = (bf16)a[1]; r[2] = (bf16)a[2]; r[3] = (bf16)a[3];
  r[4] = (bf16)b[0]; r[5] = (bf16)b[1]; r[6] = (bf16)b[2]; r[7] = (bf16)b[3];
  return r;
}

// ---------------------------------------------------------------------------
// fp32 -> bf16 bulk convert.  grid (512, 8): y<4 -> W[y], y>=4 -> x quarter.
// ---------------------------------------------------------------------------
__global__ __launch_bounds__(256)
void cvt_kernel(const float* __restrict__ x,
                const float* __restrict__ w0, const float* __restrict__ w1,
                const float* __restrict__ w2, const float* __restrict__ w3,
                bf16* __restrict__ xb, bf16* __restrict__ wb) {
  const int y = blockIdx.y;
  const float* src;
  bf16* dst;
  if (y < 4) {
    src = (y == 0) ? w0 : (y == 1) ? w1 : (y == 2) ? w2 : w3;
    dst = wb + (size_t)y * 1048576;
  } else {
    src = x + (size_t)(y - 4) * 1048576;
    dst = xb + (size_t)(y - 4) * 1048576;
  }
  const int i = (blockIdx.x * 256 + threadIdx.x) * 8;
  *(bf16x8*)(dst + i) = load8(src + i);
}

// ---------------------------------------------------------------------------
// GEMM (BK=64, 128x128 tile): C[m,n] = (sum_k X[m,k]*W[n,k]) * scale[n] [*emul]
// three=1: 8 n-tiles per W; mode1 (Q/K) -> [B,H,S,64] coalesced LDS-transpose
//   epilogue (Q gets emul=0.125*log2e); mode2 (V) -> [B,H,64,S] key-permuted.
// three=0 (mode 0): fp32 row-major out via coalesced rotated-LDS epilogue.
// ---------------------------------------------------------------------------
template <typename XT, typename WT>
__global__ __launch_bounds__(256, 2)
void gemm_kernel(const XT* __restrict__ X,
                 const WT* __restrict__ W0, const WT* __restrict__ W1,
                 const WT* __restrict__ W2,
                 const float* __restrict__ s0, const float* __restrict__ s1,
                 const float* __restrict__ s2,
                 bf16* __restrict__ o0, bf16* __restrict__ o1,
                 bf16* __restrict__ o2, float* __restrict__ ofp, int three) {
  constexpr bool ASYNC_A = (sizeof(XT) == 2);
  constexpr bool ASYNC_B = (sizeof(WT) == 2);
  __shared__ bf16 As[128 * 64];    // [row][64], chunk c^(row&7)   (16 KB)
  __shared__ bf16 Bs[128 * 64];    //                              (16 KB)

  const int t = threadIdx.x;
  const int lane = t & 63;
  const int w = t >> 6;
  const int wm = w >> 1, wn = w & 1;
  const int m0 = blockIdx.x * 128;
  const int cl = lane & 15, quad = lane >> 4;

  const WT* Wp; const float* sp; bf16* op; int mode, n0; float emul = 1.f;
  if (three) {
    int which = blockIdx.y >> 3;
    n0 = (blockIdx.y & 7) * 128;
    if (which == 0)      { Wp = W0; sp = s0; op = o0; mode = 1; emul = 0.18033688f; }
    else if (which == 1) { Wp = W1; sp = s1; op = o1; mode = 1; }
    else                 { Wp = W2; sp = s2; op = o2; mode = 2; }
  } else {
    n0 = blockIdx.y * 128; Wp = W0; sp = s0; op = o0; mode = 0;
  }

  f32x4 zero = {0.f, 0.f, 0.f, 0.f};
  f32x4 acc[4][4];
#pragma unroll
  for (int i = 0; i < 4; i++)
#pragma unroll
    for (int j = 0; j < 4; j++) acc[i][j] = zero;

  // staging geometry: thread t, round p -> row = p*32 + (t>>3),
  // phys chunk t&7, logical chunk (t&7)^(row&7) (source pre-swizzle).
  const int row64 = t >> 3;                        // 0..31
  const int lc8 = (((t & 7) ^ (row64 & 7))) * 8;   // element offset of chunk

  for (int k0 = 0; k0 < 1024; k0 += 64) {
    bf16x8 av[4], bv[4];
    if constexpr (!ASYNC_A) {
#pragma unroll
      for (int p = 0; p < 4; p++)
        av[p] = load8(&X[(uint64_t)(m0 + p * 32 + row64) * 1024 + k0 + lc8]);
    }
    if constexpr (!ASYNC_B) {
#pragma unroll
      for (int p = 0; p < 4; p++)
        bv[p] = load8(&Wp[(uint64_t)(n0 + p * 32 + row64) * 1024 + k0 + lc8]);
    }
    __syncthreads();
    if constexpr (ASYNC_A) {
#pragma unroll
      for (int p = 0; p < 4; p++)
        gl_lds16(X + (uint64_t)(m0 + p * 32 + row64) * 1024 + k0 + lc8,
                 (char*)As + p * 4096 + t * 16);
    } else {
#pragma unroll
      for (int p = 0; p < 4; p++)
        *(bf16x8*)&As[(p * 32 + row64) * 64 + (t & 7) * 8] = av[p];
    }
    if constexpr (ASYNC_B) {
#pragma unroll
      for (int p = 0; p < 4; p++)
        gl_lds16(Wp + (uint64_t)(n0 + p * 32 + row64) * 1024 + k0 + lc8,
                 (char*)Bs + p * 4096 + t * 16);
    } else {
#pragma unroll
      for (int p = 0; p < 4; p++)
        *(bf16x8*)&Bs[(p * 32 + row64) * 64 + (t & 7) * 8] = bv[p];
    }
    __syncthreads();

#pragma unroll
    for (int kkh = 0; kkh < 2; kkh++) {
      bf16x8 af[4], bfr[4];
#pragma unroll
      for (int mt = 0; mt < 4; mt++) {
        const int row = wm * 64 + mt * 16 + cl;
        af[mt] = *(const bf16x8*)&As[row * 64 +
                                     (((kkh * 4 + quad) ^ (cl & 7)) << 3)];
      }
#pragma unroll
      for (int nt = 0; nt < 4; nt++) {
        const int row = wn * 64 + nt * 16 + cl;
        bfr[nt] = *(const bf16x8*)&Bs[row * 64 +
                                      (((kkh * 4 + quad) ^ (cl & 7)) << 3)];
      }
#pragma unroll
      for (int mt = 0; mt < 4; mt++)
#pragma unroll
        for (int nt = 0; nt < 4; nt++)
          acc[mt][nt] = __builtin_amdgcn_mfma_f32_16x16x32_bf16(af[mt], bfr[nt],
                                                                acc[mt][nt],
                                                                0, 0, 0);
    }
  }

  if (mode == 1) {
    // ---- coalesced LDS-transpose epilogue (Q/K) ----
    __syncthreads();   // all waves done reading As/Bs
    bf16* slice = (bf16*)((char*)As + w * 4096);
    const int h = (n0 >> 6) + wn;
    float scv[4];
#pragma unroll
    for (int nt = 0; nt < 4; nt++)
      scv[nt] = sp[n0 + wn * 64 + nt * 16 + cl] * emul;
#pragma unroll
    for (int mt = 0; mt < 4; mt++) {
#pragma unroll
      for (int nt = 0; nt < 4; nt++)
#pragma unroll
        for (int r = 0; r < 4; r++)
          slice[(quad * 4 + r) * 72 + nt * 16 + cl] =
              (bf16)(acc[mt][nt][r] * scv[nt]);
#pragma unroll
      for (int rr = 0; rr < 2; rr++) {
        const int sr = rr * 8 + (lane >> 3);
        const int hdc = (lane & 7) * 8;
        bf16x8 v = *(const bf16x8*)&slice[sr * 72 + hdc];
        const int gm = m0 + wm * 64 + mt * 16 + sr;
        const int bb = gm >> 11, ss = gm & 2047;
        *(bf16x8*)&op[((uint64_t)(bb * 16 + h) * 2048 + ss) * 64 + hdc] = v;
      }
    }
  } else if (mode == 0) {
    // ---- coalesced fp32 epilogue (Wo output) ----
    __syncthreads();   // all waves done reading As/Bs
    float* slice = (float*)((char*)As + w * 4096);   // 16x64 f32 per wave
    float scv[4];
#pragma unroll
    for (int nt = 0; nt < 4; nt++)
      scv[nt] = sp[n0 + wn * 64 + nt * 16 + cl];
#pragma unroll
    for (int mt = 0; mt < 4; mt++) {
#pragma unroll
      for (int nt = 0; nt < 4; nt++)
#pragma unroll
        for (int r = 0; r < 4; r++) {
          const int row = quad * 4 + r;
          const int col = nt * 16 + cl;
          slice[row * 64 + ((col + 4 * row) & 63)] = acc[mt][nt][r] * scv[nt];
        }
#pragma unroll
      for (int p = 0; p < 4; p++) {
        const int sr = p * 4 + quad;
        const int c4 = cl * 4;
        f32x4 v = *(const f32x4*)&slice[sr * 64 + ((c4 + 4 * sr) & 63)];
        const int gm = m0 + wm * 64 + mt * 16 + sr;
        *(f32x4*)&ofp[(uint64_t)gm * 1024 + n0 + wn * 64 + c4] = v;
      }
    }
  } else {
    // ---- mode 2 (V): scalar stores with key-permute ----
#pragma unroll
    for (int nt = 0; nt < 4; nt++) {
      const int gn = n0 + wn * 64 + nt * 16 + cl;
      const float sc = sp[gn];
#pragma unroll
      for (int mt = 0; mt < 4; mt++) {
        const int gmb = m0 + wm * 64 + mt * 16 + quad * 4;
#pragma unroll
        for (int r = 0; r < 4; r++) {
          const int gm = gmb + r;
          const float v = acc[mt][nt][r] * sc;
          const int b = gm >> 11, s = gm & 2047;
          const int h = gn >> 6, hd = gn & 63;
          // key-permute within each 32-block: p = qd*8 + knt*4 + r
          const int sp2 = (s & ~31) |
                          ((s & 3) | (((s >> 2) & 3) << 3) | (((s >> 4) & 1) << 2));
          uint64_t addr = ((uint64_t)(b * 16 + h) * 64 + hd) * 2048 + sp2;
          op[addr] = (bf16)v;
        }
      }
    }
  }
}

// ---------------------------------------------------------------------------
// Flash attention v13: 4 waves (256 threads), Q-tile 64, grid 1024 (4
// blocks/CU = 4 independent barrier domains).  Wave split 2x2 (wq x wk):
// per-wave 32q x 32k, byte-identical compute to v12 (register-P, permuted-V
// single-b128 B-frag, MFMA ones-column l).  XCD swizzle: xcd=id&7, kk=id>>3,
// bh=xcd*4+(kk>>5), qt=kk&31, q0=qt*64.
// Epilogue: 2-way wk combine via 16KB Obuf aliasing the K/V region.
// ---------------------------------------------------------------------------
__global__ __launch_bounds__(256, 4)
void attn_kernel(const bf16* __restrict__ Qw, const bf16* __restrict__ Kw,
                 const bf16* __restrict__ Vtw, bf16* __restrict__ Ctx) {
  // loop: [0,8K) Ks | [8K,16K) Vs.  epilogue: Obuf[2][2048] fp32 on [0,16K).
  __shared__ char smem[16384];
  __shared__ float Lbuf[128];           // [w][32 queries]

  bf16* Ks = (bf16*)smem;               // [key][d], chunk c^(key&7)
  bf16* Vs = (bf16*)(smem + 8192);      // [hd][key-permuted], chunk c^(hd&7)
  float* Ob = (float*)smem;             // epilogue alias

  const int t = threadIdx.x, lane = t & 63, w = t >> 6;
  const int cl = lane & 15, quad = lane >> 4;
  const int wq = w >> 1, wk = w & 1;

  const int id = blockIdx.x;
  const int xcd = id & 7, kk = id >> 3;
  const int bh = xcd * 4 + (kk >> 5);
  const int qt = kk & 31;
  const int b = bh >> 4, h = bh & 15;
  const int q0 = qt * 64;

  const bf16* Qh = Qw + (uint64_t)bh * 2048 * 64;
  const bf16* Kh = Kw + (uint64_t)bh * 2048 * 64;
  const bf16* Vh = Vtw + (uint64_t)bh * 64 * 2048;

  // Q B-fragments: B[k=h*32+quad*8+j][n=cl], queries q0+wq*32+mt*16+cl
  bf16x8 qf[2][2];
#pragma unroll
  for (int mt = 0; mt < 2; mt++) {
    const int r = q0 + wq * 32 + mt * 16 + cl;
    qf[mt][0] = *(const bf16x8*)&Qh[(uint64_t)r * 64 + quad * 8];
    qf[mt][1] = *(const bf16x8*)&Qh[(uint64_t)r * 64 + 32 + quad * 8];
  }

  bf16x8 vones;
#pragma unroll
  for (int j = 0; j < 8; j++) vones[j] = (bf16)1.0f;

  f32x4 zero = {0.f, 0.f, 0.f, 0.f};
  f32x4 o_acc[2][4];
  f32x4 l_acc[2];
#pragma unroll
  for (int mt = 0; mt < 2; mt++) {
    l_acc[mt] = zero;
#pragma unroll
    for (int nt = 0; nt < 4; nt++) o_acc[mt][nt] = zero;
  }

  const int srow = t >> 3;                         // 0..31
  const int gcol_sw = ((t & 7) ^ (srow & 7)) * 8;  // swizzled source col
  const int lcV = wk * 4 + quad;                   // V b128 logical chunk

  for (int k0 = 0; k0 < 2048; k0 += 64) {
    __syncthreads();
    gl_lds16(Kh + (uint64_t)(k0 + srow) * 64 + gcol_sw,        (char*)Ks + t * 16);
    gl_lds16(Kh + (uint64_t)(k0 + 32 + srow) * 64 + gcol_sw,   (char*)Ks + 4096 + t * 16);
    gl_lds16(Vh + (uint64_t)srow * 2048 + k0 + gcol_sw,        (char*)Vs + t * 16);
    gl_lds16(Vh + (uint64_t)(32 + srow) * 2048 + k0 + gcol_sw, (char*)Vs + 4096 + t * 16);
    __syncthreads();   // tiles resident

    // K A-frags for this wave's 32-key half
    bf16x8 kf[2][2];
#pragma unroll
    for (int knt = 0; knt < 2; knt++) {
      const int krow = wk * 32 + knt * 16 + cl;
#pragma unroll
      for (int hh = 0; hh < 2; hh++)
        kf[knt][hh] = *(const bf16x8*)&Ks[krow * 64 +
                                          (((hh * 4 + quad) ^ (cl & 7)) << 3)];
    }
    // V B-frags: single b128 of permuted V (contraction units {2q,2q+1})
    bf16x8 vf[4];
#pragma unroll
    for (int nt = 0; nt < 4; nt++)
      vf[nt] = *(const bf16x8*)&Vs[(nt * 16 + cl) * 64 +
                                   ((lcV ^ (cl & 7)) << 3)];

    // Per mt: S^T (log2 units) -> exp2 -> pk (registers) -> PV + l-MFMA
#pragma unroll
    for (int mt = 0; mt < 2; mt++) {
      bf16x4 pk[2];
#pragma unroll
      for (int knt = 0; knt < 2; knt++) {
        f32x4 s = __builtin_amdgcn_mfma_f32_16x16x32_bf16(kf[knt][0], qf[mt][0],
                                                          zero, 0, 0, 0);
        s = __builtin_amdgcn_mfma_f32_16x16x32_bf16(kf[knt][1], qf[mt][1], s, 0, 0, 0);
#pragma unroll
        for (int r = 0; r < 4; r++)
          pk[knt][r] = (bf16)__builtin_amdgcn_exp2f(s[r]);
      }
      union { bf16x4 h[2]; bf16x8 v; } pf;
      pf.h[0] = pk[0];   // half0 keys quad*4+0..3  (contraction j=0..3)
      pf.h[1] = pk[1];   // half1 keys quad*4+0..3  (contraction j=4..7)
#pragma unroll
      for (int nt = 0; nt < 4; nt++)
        o_acc[mt][nt] = __builtin_amdgcn_mfma_f32_16x16x32_bf16(pf.v, vf[nt],
                                                                o_acc[mt][nt],
                                                                0, 0, 0);
      l_acc[mt] = __builtin_amdgcn_mfma_f32_16x16x32_bf16(pf.v, vones,
                                                          l_acc[mt], 0, 0, 0);
    }
  }

  // ---- epilogue: l_acc[mt][r] = l for query mt*16+quad*4+r (dup over cl) ----
#pragma unroll
  for (int mt = 0; mt < 2; mt++)
    if (cl == 0) *(f32x4*)&Lbuf[w * 32 + mt * 16 + quad * 4] = l_acc[mt];
  __syncthreads();            // loop reads done -> smem reusable for Obuf
  if (wk == 1) {
#pragma unroll
    for (int mt = 0; mt < 2; mt++)
#pragma unroll
      for (int nt = 0; nt < 4; nt++)
        *(f32x4*)&Ob[wq * 2048 + (mt * 4 + nt) * 256 + lane * 4] = o_acc[mt][nt];
  }
  __syncthreads();
  if (wk == 0) {
#pragma unroll
    for (int mt = 0; mt < 2; mt++) {
      float linv[4];
#pragma unroll
      for (int r = 0; r < 4; r++) {
        const int ql = mt * 16 + quad * 4 + r;
        linv[r] = 1.0f / (l_acc[mt][r] + Lbuf[(wq * 2 + 1) * 32 + ql]);
      }
#pragma unroll
      for (int nt = 0; nt < 4; nt++) {
        f32x4 other = *(const f32x4*)&Ob[wq * 2048 + (mt * 4 + nt) * 256 + lane * 4];
#pragma unroll
        for (int r = 0; r < 4; r++) {
          const int q = q0 + wq * 32 + mt * 16 + quad * 4 + r;
          const int hd = nt * 16 + cl;
          Ctx[(uint64_t)(b * 2048 + q) * 1024 + h * 64 + hd] =
              (bf16)((o_acc[mt][nt][r] + other[r]) * linv[r]);
        }
      }
    }
  }
}

// ---------------------------------------------------------------------------
extern "C" void kernel_launch(void* const* d_in, const int* in_sizes, int n_in,
                              void* d_out, int out_size, void* d_ws, size_t ws_size,
                              hipStream_t stream) {
  const float* x  = (const float*)d_in[0];
  const float* Wq = (const float*)d_in[1];
  const float* Wk = (const float*)d_in[2];
  const float* Wv = (const float*)d_in[3];
  const float* Wo = (const float*)d_in[4];
  const float* qs = (const float*)d_in[5];
  const float* ks = (const float*)d_in[6];
  const float* vs = (const float*)d_in[7];
  const float* os = (const float*)d_in[8];
  float* out = (float*)d_out;

  const size_t M4 = 4194304, M1 = 1048576;

  if (ws_size >= (size_t)40 * 1024 * 1024) {
    bf16* xb = (bf16*)d_ws;        // 4M bf16; reused as cw after QKV
    bf16* wb = xb + M4;            // wq|wk|wv|wo
    bf16* qw = wb + M4;
    bf16* kw = qw + M4;
    bf16* vw = kw + M4;
    bf16* cw = xb;

    cvt_kernel<<<dim3(512, 8), 256, 0, stream>>>(x, Wq, Wk, Wv, Wo, xb, wb);
    gemm_kernel<bf16, bf16><<<dim3(32, 24), 256, 0, stream>>>(
        xb, wb, wb + M1, wb + 2 * M1, qs, ks, vs, qw, kw, vw, nullptr, 1);
    attn_kernel<<<1024, 256, 0, stream>>>(qw, kw, vw, cw);
    gemm_kernel<bf16, bf16><<<dim3(32, 8), 256, 0, stream>>>(
        cw, wb + 3 * M1, nullptr, nullptr, os, nullptr, nullptr,
        nullptr, nullptr, nullptr, out, 0);
  } else {
    bf16* qw = (bf16*)d_ws;
    bf16* kw = qw + M4;
    bf16* vw = kw + M4;
    bf16* cw = vw + M4;
    gemm_kernel<float, float><<<dim3(32, 24), 256, 0, stream>>>(
        x, Wq, Wk, Wv, qs, ks, vs, qw, kw, vw, nullptr, 1);
    attn_kernel<<<1024, 256, 0, stream>>>(qw, kw, vw, cw);
    gemm_kernel<bf16, float><<<dim3(32, 8), 256, 0, stream>>>(
        cw, Wo, nullptr, nullptr, os, nullptr, nullptr,
        nullptr, nullptr, nullptr, out, 0);
  }
}

// Round 15
// 173.810 us; speedup vs baseline: 1.0462x; 1.0462x over previous
//
#include <hip/hip_runtime.h>
#include <hip/hip_bf16.h>
#include <stdint.h>

// B=2, S=2048, D=1024, H=16, Hd=64.  Inputs/outputs FP32; internal bf16 MFMA.
// R25 = R22 (171.2us, proven) + mode-2 (V) store vectorization WITHOUT the
// LDS slice (R24's LDS-slice epilogue raced on graph replay -- first launch
// passed, replays diverged; reverted per blind-reroll discipline).  The key
// permute makes r=0..3 CONTIGUOUS in the permuted s space
// (s' = base + (mt>>1)*32 + quad*8 + (mt&1)*4 + r), so the 4 scalar 2B
// stores per (nt,mt) merge into one aligned bf16x4 store: same addresses,
// bit-identical values, 4x fewer store instructions, no LDS, no barriers.
// attn v12 (8-wave, register-P, permuted-V, MFMA ones-l), BK=64 gemms,
// mode-0/1 coalesced epilogues, cvt all unchanged from R22.

typedef __bf16 bf16;
typedef __attribute__((ext_vector_type(8))) __bf16 bf16x8;
typedef __attribute__((ext_vector_type(4))) __bf16 bf16x4;
typedef __attribute__((ext_vector_type(4))) float f32x4;

#define DEVI __device__ __forceinline__

DEVI void gl_lds16(const void* g, void* l) {
  __builtin_amdgcn_global_load_lds(
      (const __attribute__((address_space(1))) void*)g,
      (__attribute__((address_space(3))) void*)l, 16, 0, 0);
}

DEVI bf16x8 load8(const bf16* p) { return *(const bf16x8*)p; }
DEVI bf16x8 load8(const float* p) {
  f32x4 a = *(const f32x4*)p;
  f32x4 b = *(const f32x4*)(p + 4);
  bf16x8 r;
  r[0] = (bf16)a[0]; r[1] = (bf16)a[1]; r[2] = (bf16)a[2]; r[3] = (bf16)a[3];
  r[4] = (bf16)b[0]; r[5] = (bf16)b[1]; r[6] = (bf16)b[2]; r[7] = (bf16)b[3];
  return r;
}

// ---------------------------------------------------------------------------
// fp32 -> bf16 bulk convert.  grid (512, 8): y<4 -> W[y], y>=4 -> x quarter.
// ---------------------------------------------------------------------------
__global__ __launch_bounds__(256)
void cvt_kernel(const float* __restrict__ x,
                const float* __restrict__ w0, const float* __restrict__ w1,
                const float* __restrict__ w2, const float* __restrict__ w3,
                bf16* __restrict__ xb, bf16* __restrict__ wb) {
  const int y = blockIdx.y;
  const float* src;
  bf16* dst;
  if (y < 4) {
    src = (y == 0) ? w0 : (y == 1) ? w1 : (y == 2) ? w2 : w3;
    dst = wb + (size_t)y * 1048576;
  } else {
    src = x + (size_t)(y - 4) * 1048576;
    dst = xb + (size_t)(y - 4) * 1048576;
  }
  const int i = (blockIdx.x * 256 + threadIdx.x) * 8;
  *(bf16x8*)(dst + i) = load8(src + i);
}

// ---------------------------------------------------------------------------
// GEMM (BK=64, 128x128 tile): C[m,n] = (sum_k X[m,k]*W[n,k]) * scale[n] [*emul]
// three=1: 8 n-tiles per W; mode1 (Q/K) -> [B,H,S,64] coalesced LDS-transpose
//   epilogue (Q gets emul=0.125*log2e); mode2 (V) -> [B,H,64,S] key-permuted,
//   bf16x4-vectorized stores (permute makes r contiguous).
// three=0 (mode 0): fp32 row-major out via coalesced rotated-LDS epilogue.
// ---------------------------------------------------------------------------
template <typename XT, typename WT>
__global__ __launch_bounds__(256, 2)
void gemm_kernel(const XT* __restrict__ X,
                 const WT* __restrict__ W0, const WT* __restrict__ W1,
                 const WT* __restrict__ W2,
                 const float* __restrict__ s0, const float* __restrict__ s1,
                 const float* __restrict__ s2,
                 bf16* __restrict__ o0, bf16* __restrict__ o1,
                 bf16* __restrict__ o2, float* __restrict__ ofp, int three) {
  constexpr bool ASYNC_A = (sizeof(XT) == 2);
  constexpr bool ASYNC_B = (sizeof(WT) == 2);
  __shared__ bf16 As[128 * 64];    // [row][64], chunk c^(row&7)   (16 KB)
  __shared__ bf16 Bs[128 * 64];    //                              (16 KB)

  const int t = threadIdx.x;
  const int lane = t & 63;
  const int w = t >> 6;
  const int wm = w >> 1, wn = w & 1;
  const int m0 = blockIdx.x * 128;
  const int cl = lane & 15, quad = lane >> 4;

  const WT* Wp; const float* sp; bf16* op; int mode, n0; float emul = 1.f;
  if (three) {
    int which = blockIdx.y >> 3;
    n0 = (blockIdx.y & 7) * 128;
    if (which == 0)      { Wp = W0; sp = s0; op = o0; mode = 1; emul = 0.18033688f; }
    else if (which == 1) { Wp = W1; sp = s1; op = o1; mode = 1; }
    else                 { Wp = W2; sp = s2; op = o2; mode = 2; }
  } else {
    n0 = blockIdx.y * 128; Wp = W0; sp = s0; op = o0; mode = 0;
  }

  f32x4 zero = {0.f, 0.f, 0.f, 0.f};
  f32x4 acc[4][4];
#pragma unroll
  for (int i = 0; i < 4; i++)
#pragma unroll
    for (int j = 0; j < 4; j++) acc[i][j] = zero;

  // staging geometry: thread t, round p -> row = p*32 + (t>>3),
  // phys chunk t&7, logical chunk (t&7)^(row&7) (source pre-swizzle).
  const int row64 = t >> 3;                        // 0..31
  const int lc8 = (((t & 7) ^ (row64 & 7))) * 8;   // element offset of chunk

  for (int k0 = 0; k0 < 1024; k0 += 64) {
    bf16x8 av[4], bv[4];
    if constexpr (!ASYNC_A) {
#pragma unroll
      for (int p = 0; p < 4; p++)
        av[p] = load8(&X[(uint64_t)(m0 + p * 32 + row64) * 1024 + k0 + lc8]);
    }
    if constexpr (!ASYNC_B) {
#pragma unroll
      for (int p = 0; p < 4; p++)
        bv[p] = load8(&Wp[(uint64_t)(n0 + p * 32 + row64) * 1024 + k0 + lc8]);
    }
    __syncthreads();
    if constexpr (ASYNC_A) {
#pragma unroll
      for (int p = 0; p < 4; p++)
        gl_lds16(X + (uint64_t)(m0 + p * 32 + row64) * 1024 + k0 + lc8,
                 (char*)As + p * 4096 + t * 16);
    } else {
#pragma unroll
      for (int p = 0; p < 4; p++)
        *(bf16x8*)&As[(p * 32 + row64) * 64 + (t & 7) * 8] = av[p];
    }
    if constexpr (ASYNC_B) {
#pragma unroll
      for (int p = 0; p < 4; p++)
        gl_lds16(Wp + (uint64_t)(n0 + p * 32 + row64) * 1024 + k0 + lc8,
                 (char*)Bs + p * 4096 + t * 16);
    } else {
#pragma unroll
      for (int p = 0; p < 4; p++)
        *(bf16x8*)&Bs[(p * 32 + row64) * 64 + (t & 7) * 8] = bv[p];
    }
    __syncthreads();

#pragma unroll
    for (int kkh = 0; kkh < 2; kkh++) {
      bf16x8 af[4], bfr[4];
#pragma unroll
      for (int mt = 0; mt < 4; mt++) {
        const int row = wm * 64 + mt * 16 + cl;
        af[mt] = *(const bf16x8*)&As[row * 64 +
                                     (((kkh * 4 + quad) ^ (cl & 7)) << 3)];
      }
#pragma unroll
      for (int nt = 0; nt < 4; nt++) {
        const int row = wn * 64 + nt * 16 + cl;
        bfr[nt] = *(const bf16x8*)&Bs[row * 64 +
                                      (((kkh * 4 + quad) ^ (cl & 7)) << 3)];
      }
#pragma unroll
      for (int mt = 0; mt < 4; mt++)
#pragma unroll
        for (int nt = 0; nt < 4; nt++)
          acc[mt][nt] = __builtin_amdgcn_mfma_f32_16x16x32_bf16(af[mt], bfr[nt],
                                                                acc[mt][nt],
                                                                0, 0, 0);
    }
  }

  if (mode == 1) {
    // ---- coalesced LDS-transpose epilogue (Q/K) ----
    __syncthreads();   // all waves done reading As/Bs
    bf16* slice = (bf16*)((char*)As + w * 4096);
    const int h = (n0 >> 6) + wn;
    float scv[4];
#pragma unroll
    for (int nt = 0; nt < 4; nt++)
      scv[nt] = sp[n0 + wn * 64 + nt * 16 + cl] * emul;
#pragma unroll
    for (int mt = 0; mt < 4; mt++) {
#pragma unroll
      for (int nt = 0; nt < 4; nt++)
#pragma unroll
        for (int r = 0; r < 4; r++)
          slice[(quad * 4 + r) * 72 + nt * 16 + cl] =
              (bf16)(acc[mt][nt][r] * scv[nt]);
#pragma unroll
      for (int rr = 0; rr < 2; rr++) {
        const int sr = rr * 8 + (lane >> 3);
        const int hdc = (lane & 7) * 8;
        bf16x8 v = *(const bf16x8*)&slice[sr * 72 + hdc];
        const int gm = m0 + wm * 64 + mt * 16 + sr;
        const int bb = gm >> 11, ss = gm & 2047;
        *(bf16x8*)&op[((uint64_t)(bb * 16 + h) * 2048 + ss) * 64 + hdc] = v;
      }
    }
  } else if (mode == 0) {
    // ---- coalesced fp32 epilogue (Wo output) ----
    __syncthreads();   // all waves done reading As/Bs
    float* slice = (float*)((char*)As + w * 4096);   // 16x64 f32 per wave
    float scv[4];
#pragma unroll
    for (int nt = 0; nt < 4; nt++)
      scv[nt] = sp[n0 + wn * 64 + nt * 16 + cl];
#pragma unroll
    for (int mt = 0; mt < 4; mt++) {
#pragma unroll
      for (int nt = 0; nt < 4; nt++)
#pragma unroll
        for (int r = 0; r < 4; r++) {
          const int row = quad * 4 + r;
          const int col = nt * 16 + cl;
          slice[row * 64 + ((col + 4 * row) & 63)] = acc[mt][nt][r] * scv[nt];
        }
#pragma unroll
      for (int p = 0; p < 4; p++) {
        const int sr = p * 4 + quad;
        const int c4 = cl * 4;
        f32x4 v = *(const f32x4*)&slice[sr * 64 + ((c4 + 4 * sr) & 63)];
        const int gm = m0 + wm * 64 + mt * 16 + sr;
        *(f32x4*)&ofp[(uint64_t)gm * 1024 + n0 + wn * 64 + c4] = v;
      }
    }
  } else {
    // ---- mode 2 (V): key-permuted bf16x4 stores (no LDS) ----
    // Permute makes r=0..3 contiguous: s' = ss0 + (mt>>1)*32 + quad*8 +
    // (mt&1)*4 + r.  One aligned 8B store per (nt,mt) replaces 4 scalar 2B.
    const int bb = (m0 + wm * 64) >> 11;
    const int ss0 = (m0 + wm * 64) & 2047;
#pragma unroll
    for (int nt = 0; nt < 4; nt++) {
      const int gn = n0 + wn * 64 + nt * 16 + cl;
      const float sc = sp[gn];
      const int h = gn >> 6, hd = gn & 63;
#pragma unroll
      for (int mt = 0; mt < 4; mt++) {
        bf16x4 pk;
#pragma unroll
        for (int r = 0; r < 4; r++) pk[r] = (bf16)(acc[mt][nt][r] * sc);
        const int sp2 = ss0 + (mt >> 1) * 32 + quad * 8 + (mt & 1) * 4;
        *(bf16x4*)&op[((uint64_t)(bb * 16 + h) * 64 + hd) * 2048 + sp2] = pk;
      }
    }
  }
}

// ---------------------------------------------------------------------------
// Flash attention v12: 8 waves (512 threads), wave split 4x2 (wq x wk),
// single-buffered 2-barrier loop, P register-resident, V key-permuted in
// memory (single-b128 PV B-frag), softmax denominator via MFMA ones-column.
// Epilogue: cross-wave (wk) O+l combine via LDS; Obuf aliases K/V region.
// ---------------------------------------------------------------------------
__global__ __launch_bounds__(512, 4)
void attn_kernel(const bf16* __restrict__ Qw, const bf16* __restrict__ Kw,
                 const bf16* __restrict__ Vtw, bf16* __restrict__ Ctx) {
  // loop: [0,8K) Ks | [8K,16K) Vs.  epilogue: Obuf[4][2048] fp32 on [0,32K).
  __shared__ char smem[32768];
  __shared__ float Lbuf[256];           // [wq*2+wk][32 queries]

  bf16* Ks = (bf16*)smem;               // [key][d], chunk c^(key&7)
  bf16* Vs = (bf16*)(smem + 8192);      // [hd][key-permuted], chunk c^(hd&7)
  float* Ob = (float*)smem;             // epilogue alias

  const int t = threadIdx.x, lane = t & 63, w = t >> 6;
  const int cl = lane & 15, quad = lane >> 4;
  const int wq = w >> 1, wk = w & 1;

  const int id = blockIdx.x;
  const int xcd = id & 7, kk = id >> 3;
  const int bh = xcd * 4 + (kk >> 4);
  const int qt = kk & 15;
  const int b = bh >> 4, h = bh & 15;
  const int q0 = qt * 128;

  const bf16* Qh = Qw + (uint64_t)bh * 2048 * 64;
  const bf16* Kh = Kw + (uint64_t)bh * 2048 * 64;
  const bf16* Vh = Vtw + (uint64_t)bh * 64 * 2048;

  // Q B-fragments: B[k=h*32+quad*8+j][n=cl], queries q0+wq*32+mt*16+cl
  bf16x8 qf[2][2];
#pragma unroll
  for (int mt = 0; mt < 2; mt++) {
    const int r = q0 + wq * 32 + mt * 16 + cl;
    qf[mt][0] = *(const bf16x8*)&Qh[(uint64_t)r * 64 + quad * 8];
    qf[mt][1] = *(const bf16x8*)&Qh[(uint64_t)r * 64 + 32 + quad * 8];
  }

  bf16x8 vones;
#pragma unroll
  for (int j = 0; j < 8; j++) vones[j] = (bf16)1.0f;

  f32x4 zero = {0.f, 0.f, 0.f, 0.f};
  f32x4 o_acc[2][4];
  f32x4 l_acc[2];
#pragma unroll
  for (int mt = 0; mt < 2; mt++) {
    l_acc[mt] = zero;
#pragma unroll
    for (int nt = 0; nt < 4; nt++) o_acc[mt][nt] = zero;
  }

  const int srow = t >> 3;                         // 0..63
  const int gcol_sw = ((t & 7) ^ (srow & 7)) * 8;  // swizzled source col
  const int lcV = wk * 4 + quad;                   // V b128 logical chunk

  for (int k0 = 0; k0 < 2048; k0 += 64) {
    __syncthreads();
    gl_lds16(Kh + (uint64_t)(k0 + srow) * 64 + gcol_sw, (char*)Ks + t * 16);
    gl_lds16(Vh + (uint64_t)srow * 2048 + k0 + gcol_sw, (char*)Vs + t * 16);
    __syncthreads();   // tiles resident

    // K A-frags for this wave's 32-key half
    bf16x8 kf[2][2];
#pragma unroll
    for (int knt = 0; knt < 2; knt++) {
      const int krow = wk * 32 + knt * 16 + cl;
#pragma unroll
      for (int hh = 0; hh < 2; hh++)
        kf[knt][hh] = *(const bf16x8*)&Ks[krow * 64 +
                                          (((hh * 4 + quad) ^ (cl & 7)) << 3)];
    }
    // V B-frags: single b128 of permuted V (contraction units {2q,2q+1})
    bf16x8 vf[4];
#pragma unroll
    for (int nt = 0; nt < 4; nt++)
      vf[nt] = *(const bf16x8*)&Vs[(nt * 16 + cl) * 64 +
                                   ((lcV ^ (cl & 7)) << 3)];

    // Per mt: S^T (log2 units) -> exp2 -> pk (registers) -> PV + l-MFMA
#pragma unroll
    for (int mt = 0; mt < 2; mt++) {
      bf16x4 pk[2];
#pragma unroll
      for (int knt = 0; knt < 2; knt++) {
        f32x4 s = __builtin_amdgcn_mfma_f32_16x16x32_bf16(kf[knt][0], qf[mt][0],
                                                          zero, 0, 0, 0);
        s = __builtin_amdgcn_mfma_f32_16x16x32_bf16(kf[knt][1], qf[mt][1], s, 0, 0, 0);
#pragma unroll
        for (int r = 0; r < 4; r++)
          pk[knt][r] = (bf16)__builtin_amdgcn_exp2f(s[r]);
      }
      union { bf16x4 h[2]; bf16x8 v; } pf;
      pf.h[0] = pk[0];   // half0 keys quad*4+0..3  (contraction j=0..3)
      pf.h[1] = pk[1];   // half1 keys quad*4+0..3  (contraction j=4..7)
#pragma unroll
      for (int nt = 0; nt < 4; nt++)
        o_acc[mt][nt] = __builtin_amdgcn_mfma_f32_16x16x32_bf16(pf.v, vf[nt],
                                                                o_acc[mt][nt],
                                                                0, 0, 0);
      l_acc[mt] = __builtin_amdgcn_mfma_f32_16x16x32_bf16(pf.v, vones,
                                                          l_acc[mt], 0, 0, 0);
    }
  }

  // ---- epilogue: l_acc[mt][r] = l for query mt*16+quad*4+r (dup over cl) ----
#pragma unroll
  for (int mt = 0; mt < 2; mt++)
    if (cl == 0) *(f32x4*)&Lbuf[w * 32 + mt * 16 + quad * 4] = l_acc[mt];
  __syncthreads();            // loop reads done -> smem reusable for Obuf
  if (wk == 1) {
#pragma unroll
    for (int mt = 0; mt < 2; mt++)
#pragma unroll
      for (int nt = 0; nt < 4; nt++)
        *(f32x4*)&Ob[wq * 2048 + (mt * 4 + nt) * 256 + lane * 4] = o_acc[mt][nt];
  }
  __syncthreads();
  if (wk == 0) {
#pragma unroll
    for (int mt = 0; mt < 2; mt++) {
      float linv[4];
#pragma unroll
      for (int r = 0; r < 4; r++) {
        const int ql = mt * 16 + quad * 4 + r;
        linv[r] = 1.0f / (l_acc[mt][r] + Lbuf[(wq * 2 + 1) * 32 + ql]);
      }
#pragma unroll
      for (int nt = 0; nt < 4; nt++) {
        f32x4 other = *(const f32x4*)&Ob[wq * 2048 + (mt * 4 + nt) * 256 + lane * 4];
#pragma unroll
        for (int r = 0; r < 4; r++) {
          const int q = q0 + wq * 32 + mt * 16 + quad * 4 + r;
          const int hd = nt * 16 + cl;
          Ctx[(uint64_t)(b * 2048 + q) * 1024 + h * 64 + hd] =
              (bf16)((o_acc[mt][nt][r] + other[r]) * linv[r]);
        }
      }
    }
  }
}

// ---------------------------------------------------------------------------
extern "C" void kernel_launch(void* const* d_in, const int* in_sizes, int n_in,
                              void* d_out, int out_size, void* d_ws, size_t ws_size,
                              hipStream_t stream) {
  const float* x  = (const float*)d_in[0];
  const float* Wq = (const float*)d_in[1];
  const float* Wk = (const float*)d_in[2];
  const float* Wv = (const float*)d_in[3];
  const float* Wo = (const float*)d_in[4];
  const float* qs = (const float*)d_in[5];
  const float* ks = (const float*)d_in[6];
  const float* vs = (const float*)d_in[7];
  const float* os = (const float*)d_in[8];
  float* out = (float*)d_out;

  const size_t M4 = 4194304, M1 = 1048576;

  if (ws_size >= (size_t)40 * 1024 * 1024) {
    bf16* xb = (bf16*)d_ws;        // 4M bf16; reused as cw after QKV
    bf16* wb = xb + M4;            // wq|wk|wv|wo
    bf16* qw = wb + M4;
    bf16* kw = qw + M4;
    bf16* vw = kw + M4;
    bf16* cw = xb;

    cvt_kernel<<<dim3(512, 8), 256, 0, stream>>>(x, Wq, Wk, Wv, Wo, xb, wb);
    gemm_kernel<bf16, bf16><<<dim3(32, 24), 256, 0, stream>>>(
        xb, wb, wb + M1, wb + 2 * M1, qs, ks, vs, qw, kw, vw, nullptr, 1);
    attn_kernel<<<512, 512, 0, stream>>>(qw, kw, vw, cw);
    gemm_kernel<bf16, bf16><<<dim3(32, 8), 256, 0, stream>>>(
        cw, wb + 3 * M1, nullptr, nullptr, os, nullptr, nullptr,
        nullptr, nullptr, nullptr, out, 0);
  } else {
    bf16* qw = (bf16*)d_ws;
    bf16* kw = qw + M4;
    bf16* vw = kw + M4;
    bf16* cw = vw + M4;
    gemm_kernel<float, float><<<dim3(32, 24), 256, 0, stream>>>(
        x, Wq, Wk, Wv, qs, ks, vs, qw, kw, vw, nullptr, 1);
    attn_kernel<<<512, 512, 0, stream>>>(qw, kw, vw, cw);
    gemm_kernel<bf16, float><<<dim3(32, 8), 256, 0, stream>>>(
        cw, Wo, nullptr, nullptr, os, nullptr, nullptr,
        nullptr, nullptr, nullptr, out, 0);
  }
}